// Round 7
// baseline (261.446 us; speedup 1.0000x reference)
//
#include <hip/hip_runtime.h>

#define B_ 2
#define S_ 2048
#define E_ 1024
#define H_ 16
#define D_ 64

typedef short  s16x8 __attribute__((ext_vector_type(8)));
typedef float  f32x4 __attribute__((ext_vector_type(4)));
typedef unsigned short u16x4 __attribute__((ext_vector_type(4)));

__device__ __forceinline__ ushort f2bf(float f) {
    union { float f; unsigned u; } x; x.f = f;
    unsigned u = x.u + 0x7fffu + ((x.u >> 16) & 1u);   // RNE
    return (ushort)(u >> 16);
}

__device__ __forceinline__ float fast_exp2(float x) {
    float r; asm("v_exp_f32 %0, %1" : "=v"(r) : "v"(x)); return r;
}

// ---------------------------------------------------------------------------
// X fp32 -> bf16 (flat, 4 elems/thread)
// ---------------------------------------------------------------------------
__global__ __launch_bounds__(256) void cvtx_kernel(
    const float* __restrict__ X, ushort* __restrict__ Xbf)
{
    int i = (blockIdx.x * 256 + threadIdx.x) * 4;
    float4 v = *(const float4*)&X[i];
    u16x4 o;
    o.x = f2bf(v.x); o.y = f2bf(v.y); o.z = f2bf(v.z); o.w = f2bf(v.w);
    *(u16x4*)&Xbf[i] = o;
}

// ---------------------------------------------------------------------------
// W fp32 [Kdim][Ndim] -> Wt bf16 [Ndim][Kdim]  (64x64 LDS tiles)
// ---------------------------------------------------------------------------
__global__ __launch_bounds__(256) void wtrans_kernel(
    const float* __restrict__ W, ushort* __restrict__ Wt, int Kdim, int Ndim)
{
    __shared__ float tile[64][65];
    int n0 = blockIdx.x * 64, k0 = blockIdx.y * 64;
    int tid = threadIdx.x;
    int c = tid & 63;
#pragma unroll
    for (int r = tid >> 6; r < 64; r += 4)
        tile[r][c] = W[(size_t)(k0 + r) * Ndim + n0 + c];
    __syncthreads();
#pragma unroll
    for (int r = tid >> 6; r < 64; r += 4)
        Wt[(size_t)(n0 + r) * Kdim + k0 + c] = f2bf(tile[c][r]);
}

// ---------------------------------------------------------------------------
// bias fp32 [S][S] -> biasT bf16, causal-packed tile layout, pre-scaled by
// log2(e).  Tile (qi,ki), ki<=qi, L = qi(qi+1)/2 + ki.
// biasT[L*4096 + tid*16 + (r*4+kt)] with tid = w*64 + quad*16 + l15 encoding
// (row16grp w, quad, l15).  16 bias values per consumer-thread CONTIGUOUS.
// ---------------------------------------------------------------------------
__global__ __launch_bounds__(256) void prep_bias_kernel(
    const float* __restrict__ bias, ushort* __restrict__ biasT)
{
    int L = blockIdx.x;
    int qi = (int)((sqrtf(8.0f * (float)L + 1.0f) - 1.0f) * 0.5f);
    while ((qi + 1) * (qi + 2) / 2 <= L) qi++;
    while (qi * (qi + 1) / 2 > L) qi--;
    int ki = L - qi * (qi + 1) / 2;
    int tid = threadIdx.x;
    int w = tid >> 6, quad = (tid >> 4) & 3, l15 = tid & 15;
    const float LOG2E = 1.4426950408889634f;
    s16x8 h0 = (s16x8){0,0,0,0,0,0,0,0}, h1 = (s16x8){0,0,0,0,0,0,0,0};
#pragma unroll
    for (int r = 0; r < 4; r++)
#pragma unroll
        for (int kt = 0; kt < 4; kt++) {
            float v = bias[(size_t)(qi * 64 + w * 16 + quad * 4 + r) * S_
                           + ki * 64 + kt * 16 + l15] * LOG2E;
            ushort u = f2bf(v);
            int idx = r * 4 + kt;
            if (idx < 8) h0[idx] = (short)u; else h1[idx - 8] = (short)u;
        }
    ushort* dst = &biasT[((size_t)L * 256 + tid) * 16];
    *(s16x8*)dst = h0;
    *(s16x8*)(dst + 8) = h1;
}

// ---------------------------------------------------------------------------
// bf16 MFMA GEMM (m97 structure): C[m][n] = sum_k A[m][k]*Bt[n][k] + bias[n]
// ---------------------------------------------------------------------------
__global__ __launch_bounds__(256) void gemm_mfma_bt(
    const ushort* __restrict__ A,    // [M][K] bf16
    const ushort* __restrict__ Bt,   // [N][K] bf16
    const float* __restrict__ bias,  // [N]
    int M, int N, int K,
    float* __restrict__ C0,
    ushort* __restrict__ Qbf, float* __restrict__ Kf32, ushort* __restrict__ Kbf,
    float* __restrict__ Vf32, int mode)
{
    __shared__ ushort As[128 * 32];
    __shared__ ushort Bs[128 * 32];
    int tid = threadIdx.x;
    int wid = tid >> 6, lane = tid & 63;
    int l15 = lane & 15, quad = lane >> 4;
    int wm = wid >> 1, wn = wid & 1;
    int row0 = blockIdx.y * 128, col0 = blockIdx.x * 128;

    int sr = wid * 16 + (lane >> 2);
    int sk = (lane & 3) * 8;

    f32x4 acc[4][4];
#pragma unroll
    for (int mt = 0; mt < 4; mt++)
#pragma unroll
        for (int nt = 0; nt < 4; nt++) acc[mt][nt] = (f32x4){0.f, 0.f, 0.f, 0.f};

    for (int k0 = 0; k0 < K; k0 += 32) {
        __syncthreads();
#pragma unroll
        for (int c = 0; c < 2; c++) {
            int r = c * 64 + sr;
            __builtin_amdgcn_global_load_lds(
                (const __attribute__((address_space(1))) unsigned int*)
                    &A[(size_t)(row0 + r) * K + k0 + sk],
                (__attribute__((address_space(3))) unsigned int*)&As[r * 32 + sk],
                16, 0, 0);
            __builtin_amdgcn_global_load_lds(
                (const __attribute__((address_space(1))) unsigned int*)
                    &Bt[(size_t)(col0 + r) * K + k0 + sk],
                (__attribute__((address_space(3))) unsigned int*)&Bs[r * 32 + sk],
                16, 0, 0);
        }
        __syncthreads();

        s16x8 af[4], bf[4];
#pragma unroll
        for (int mt = 0; mt < 4; mt++)
            af[mt] = *(const s16x8*)&As[(wm * 64 + mt * 16 + l15) * 32 + quad * 8];
#pragma unroll
        for (int nt = 0; nt < 4; nt++)
            bf[nt] = *(const s16x8*)&Bs[(wn * 64 + nt * 16 + l15) * 32 + quad * 8];
#pragma unroll
        for (int mt = 0; mt < 4; mt++)
#pragma unroll
            for (int nt = 0; nt < 4; nt++)
                acc[mt][nt] = __builtin_amdgcn_mfma_f32_16x16x32_bf16(
                    af[mt], bf[nt], acc[mt][nt], 0, 0, 0);
    }

#pragma unroll
    for (int nt = 0; nt < 4; nt++) {
        int n = col0 + wn * 64 + nt * 16 + l15;
        float bv = bias[n];
        if (mode == 1) {
            int seg = n >> 10;
            int nn = n & (E_ - 1);
#pragma unroll
            for (int mt = 0; mt < 4; mt++)
#pragma unroll
                for (int r = 0; r < 4; r++) {
                    int row = row0 + wm * 64 + mt * 16 + quad * 4 + r;
                    float v = acc[mt][nt][r] + bv;
                    size_t idx = (size_t)row * E_ + nn;
                    if (seg == 0)      Qbf[idx] = f2bf(v);
                    else if (seg == 1) { Kf32[idx] = v; Kbf[idx] = f2bf(v); }
                    else               Vf32[idx] = v;
                }
        } else {
#pragma unroll
            for (int mt = 0; mt < 4; mt++)
#pragma unroll
                for (int r = 0; r < 4; r++) {
                    int row = row0 + wm * 64 + mt * 16 + quad * 4 + r;
                    C0[(size_t)row * N + n] = acc[mt][nt][r] + bv;
                }
        }
    }
}

// ---------------------------------------------------------------------------
// V transpose: fp32 V [b*S+s][h*64+d] -> bf16 Vt [(b*H+h)*64+d][s]
// ---------------------------------------------------------------------------
__global__ __launch_bounds__(256) void vtrans_kernel(
    const float* __restrict__ V, ushort* __restrict__ Vt)
{
    __shared__ float tile[64][65];
    int blk = blockIdx.x;
    int s0 = (blk & 31) * 64;
    int bh = blk >> 5;
    int b = bh >> 4, h = bh & 15;
    int tid = threadIdx.x;
    int d = tid & 63;
#pragma unroll
    for (int i = tid >> 6; i < 64; i += 4)
        tile[i][d] = V[((size_t)(b * S_ + s0 + i)) * E_ + h * 64 + d];
    __syncthreads();
    int lane = tid & 63, w = tid >> 6;
#pragma unroll
    for (int dd = w; dd < 64; dd += 4)
        Vt[((size_t)(bh * 64 + dd)) * S_ + s0 + lane] = f2bf(tile[lane][dd]);
}

// ---------------------------------------------------------------------------
// MFMA flash attention, fixed-reference softmax — round 12.
// R6 budget: LDS pipe ~77% busy; biggest term = K/V fragment reads, which all
// 4 waves duplicate while amortizing over only 16 q-rows each. This version
// gives each wave 32 q-rows (two A-fragments rg=0,1): q-tiles are 128 rows,
// held kb/vb fragments feed 2x the MFMAs. Per unit of work: K/V frag reads,
// staging writes, barriers, and K/V global traffic all HALVE.
// Grid: 512 blocks (g=blk>>5, Q = g<8 ? 15-g : g-8) — all blocks resident at
// t=0 (2/CU); round-robin pair (15-g', g') gives uniform 34 key-tiles/CU.
// Per-wave masking: qi64 = 2Q + (wid>>1); active t<=qi64, diag t==qi64
// (waves 0,1 predicated off on the block's last key-tile).
// VGPR grows (~170 peak) — fine: grid limits to 2 waves/SIMD, cap 256.
// K/V XOR swizzle, Ps swizzle (+rg*16 rows), biasT format, exp2 path, and the
// 2-barrier schedule are carried over from R6 unchanged.
// ---------------------------------------------------------------------------
__global__ __launch_bounds__(256) void attn_mfma_kernel(
    const ushort* __restrict__ Qbf,   // [B*S, E] bf16
    const ushort* __restrict__ Kbf,   // [B*S, E] bf16
    const ushort* __restrict__ Vt,    // [(b*H+h)*64+d][S] bf16
    const ushort* __restrict__ biasT, // causal-packed bf16 tiles (prep_bias)
    ushort* __restrict__ Ctx)         // [B*S, E] bf16
{
    __shared__ ushort Ks[64][64];
    __shared__ ushort Vs[64][64];
    __shared__ ushort Ps[4][32][72];

    int blk = blockIdx.x;
    int bh = blk & 31;               // XCD = bh%8 -> K/V L2 locality
    int g  = blk >> 5;               // 0..15
    int Q  = (g < 8) ? (15 - g) : (g - 8);   // complementary RR pairing
    int b = bh >> 4, h = bh & 15;
    int tid = threadIdx.x;
    int wid = tid >> 6, lane = tid & 63;
    int l15 = lane & 15, quad = lane >> 4;
    int hw = wid >> 1;               // which 64-half of the 128-row q-tile
    int qi64 = 2 * Q + hw;           // absolute 64-row tile idx (bias/mask)
    int tblk = 2 * Q + 1;            // last key-tile staged by the block

    int skey = tid >> 2;
    int sc0 = ((((tid & 3) * 2) ^ (skey & 7)) * 8);
    int sc1 = sc0 ^ 8;
    int scol = (tid & 3) * 16;
    const float scale_l2e = 0.18033688011112042f;   // 0.125 * log2(e)

    const size_t krow = (size_t)(b * S_ + skey) * E_ + h * 64 + scol; // + j0*E_
    const size_t vrow = (size_t)(bh * 64 + skey) * S_ + scol;         // + j0
    int rc0 = (quad ^ (l15 & 7)) * 8;

    int q0w = Q * 128 + wid * 32;    // wave's first q-row

    // Q fragments: 2 row-groups x 2 k-halves
    const size_t qb0 = ((size_t)(b * S_ + q0w + l15)) * E_ + h * 64 + quad * 8;
    s16x8 qa[2][2];
    qa[0][0] = *(const s16x8*)&Qbf[qb0];
    qa[0][1] = *(const s16x8*)&Qbf[qb0 + 32];
    qa[1][0] = *(const s16x8*)&Qbf[qb0 + (size_t)16 * E_];
    qa[1][1] = *(const s16x8*)&Qbf[qb0 + (size_t)16 * E_ + 32];

    f32x4 o[2][4];
#pragma unroll
    for (int rg = 0; rg < 2; rg++)
#pragma unroll
        for (int dt = 0; dt < 4; dt++) o[rg][dt] = (f32x4){0.f, 0.f, 0.f, 0.f};
    float lsum[2][4];
#pragma unroll
    for (int rg = 0; rg < 2; rg++)
#pragma unroll
        for (int r = 0; r < 4; r++) lsum[rg][r] = 0.f;

    // biasT base per rg: within-64-tile row16grp w' = (wid&1)*2 + rg
    const ushort* bt0 = &biasT[((size_t)(qi64 * (qi64 + 1) / 2) * 256
                                + ((wid & 1) * 2) * 64 + quad * 16 + l15) * 16];
    const ushort* bt1 = bt0 + 1024;   // rg=1: +64 in tid' -> +1024 ushorts

    // ---- preload tile 0
    float4 kr0 = ((const float4*)&Kbf[krow])[0];
    float4 kr1 = ((const float4*)&Kbf[krow])[1];
    float4 vr0 = ((const float4*)&Vt[vrow])[0];
    float4 vr1 = ((const float4*)&Vt[vrow])[1];
    s16x8 bn[2][2];
    bn[0][0] = *(const s16x8*)bt0;       bn[0][1] = *(const s16x8*)(bt0 + 8);
    bn[1][0] = *(const s16x8*)bt1;       bn[1][1] = *(const s16x8*)(bt1 + 8);

    for (int t = 0; t <= tblk; t++) {
        int j0 = t * 64;
        __syncthreads();          // prior compute done; LDS free
        *(float4*)&Ks[skey][sc0] = kr0;
        *(float4*)&Ks[skey][sc1] = kr1;
        *(float4*)&Vs[skey][sc0] = vr0;
        *(float4*)&Vs[skey][sc1] = vr1;
        s16x8 bc[2][2];
#pragma unroll
        for (int rg = 0; rg < 2; rg++) {
            bc[rg][0] = bn[rg][0]; bc[rg][1] = bn[rg][1];
        }
        __syncthreads();

        // ---- prefetch tile t+1 (registers only)
        if (t < tblk) {
            int j1 = j0 + 64;
            kr0 = ((const float4*)&Kbf[krow + (size_t)j1 * E_])[0];
            kr1 = ((const float4*)&Kbf[krow + (size_t)j1 * E_])[1];
            vr0 = ((const float4*)&Vt[vrow + j1])[0];
            vr1 = ((const float4*)&Vt[vrow + j1])[1];
        }
        if (t < qi64) {
            const ushort* p0 = bt0 + (size_t)(t + 1) * 4096;
            bn[0][0] = *(const s16x8*)p0;       bn[0][1] = *(const s16x8*)(p0 + 8);
            const ushort* p1 = bt1 + (size_t)(t + 1) * 4096;
            bn[1][0] = *(const s16x8*)p1;       bn[1][1] = *(const s16x8*)(p1 + 8);
        }

        if (t <= qi64) {
            bool diag = (t == qi64);

            // ---- K fragments once, shared across both row-groups
            s16x8 kb[4][2];
#pragma unroll
            for (int kt = 0; kt < 4; kt++) {
                kb[kt][0] = *(const s16x8*)&Ks[kt * 16 + l15][rc0];
                kb[kt][1] = *(const s16x8*)&Ks[kt * 16 + l15][rc0 ^ 32];
            }

#pragma unroll
            for (int rg = 0; rg < 2; rg++) {
                // ---- S = Q K^T
                f32x4 s[4];
#pragma unroll
                for (int kt = 0; kt < 4; kt++) {
                    f32x4 acc = (f32x4){0.f, 0.f, 0.f, 0.f};
                    acc = __builtin_amdgcn_mfma_f32_16x16x32_bf16(qa[rg][0], kb[kt][0], acc, 0, 0, 0);
                    acc = __builtin_amdgcn_mfma_f32_16x16x32_bf16(qa[rg][1], kb[kt][1], acc, 0, 0, 0);
                    s[kt] = acc;
                }
                // ---- p = exp2(s*scale + biasT); causal mask; swizzled Ps
#pragma unroll
                for (int r = 0; r < 4; r++) {
                    int row = q0w + rg * 16 + quad * 4 + r;
#pragma unroll
                    for (int kt = 0; kt < 4; kt++) {
                        int j = j0 + kt * 16 + l15;
                        int idx = r * 4 + kt;
                        ushort ub = (ushort)((idx < 8) ? bc[rg][0][idx] : bc[rg][1][idx - 8]);
                        union { unsigned u; float f; } bcv; bcv.u = ((unsigned)ub) << 16;
                        float v = fmaf(s[kt][r], scale_l2e, bcv.f);
                        float p = (diag && j > row) ? 0.f : fast_exp2(v);
                        lsum[rg][r] += p;
                        int chunk = (kt * 2 + (l15 >> 3)) ^ quad;
                        Ps[wid][rg * 16 + quad * 4 + r][chunk * 8 + (l15 & 7)] = f2bf(p);
                    }
                }
            }

            // ---- O += P V  (Ps wave-private: no barrier)
            int cb = (quad ^ (l15 >> 2)) * 8;
            s16x8 pa[2][2];
#pragma unroll
            for (int rg = 0; rg < 2; rg++) {
                pa[rg][0] = *(const s16x8*)&Ps[wid][rg * 16 + l15][cb];
                pa[rg][1] = *(const s16x8*)&Ps[wid][rg * 16 + l15][cb + 32];
            }
#pragma unroll
            for (int dt = 0; dt < 4; dt++) {
                s16x8 vb0 = *(const s16x8*)&Vs[dt * 16 + l15][rc0];
                s16x8 vb1 = *(const s16x8*)&Vs[dt * 16 + l15][rc0 ^ 32];
#pragma unroll
                for (int rg = 0; rg < 2; rg++) {
                    o[rg][dt] = __builtin_amdgcn_mfma_f32_16x16x32_bf16(pa[rg][0], vb0, o[rg][dt], 0, 0, 0);
                    o[rg][dt] = __builtin_amdgcn_mfma_f32_16x16x32_bf16(pa[rg][1], vb1, o[rg][dt], 0, 0, 0);
                }
            }
        }
    }

    // ---- final row-sum reduction + store
#pragma unroll
    for (int rg = 0; rg < 2; rg++) {
        float inv_l[4];
#pragma unroll
        for (int r = 0; r < 4; r++) {
            float l = lsum[rg][r];
            l += __shfl_xor(l, 1);
            l += __shfl_xor(l, 2);
            l += __shfl_xor(l, 4);
            l += __shfl_xor(l, 8);
            inv_l[r] = 1.f / l;
        }
#pragma unroll
        for (int dt = 0; dt < 4; dt++) {
#pragma unroll
            for (int r = 0; r < 4; r++) {
                int row = q0w + rg * 16 + quad * 4 + r;
                Ctx[((size_t)(b * S_ + row)) * E_ + h * 64 + dt * 16 + l15] =
                    f2bf(o[rg][dt][r] * inv_l[r]);
            }
        }
    }
}

// ---------------------------------------------------------------------------
extern "C" void kernel_launch(void* const* d_in, const int* in_sizes, int n_in,
                              void* d_out, int out_size, void* d_ws, size_t ws_size,
                              hipStream_t stream) {
    const float* X     = (const float*)d_in[0];
    const float* abias = (const float*)d_in[1];
    const float* Wqkv  = (const float*)d_in[2];
    const float* bqkv  = (const float*)d_in[3];
    const float* Wproj = (const float*)d_in[4];
    const float* bproj = (const float*)d_in[5];

    const size_t plane = (size_t)B_ * S_ * E_;   // 4,194,304
    float* out  = (float*)d_out;
    float* kout = out + plane;                   // cache_key (fp32 output)
    float* vout = kout + plane;                  // cache_value (fp32 output)

    ushort* xbf    = (ushort*)d_ws;
    ushort* qbf    = xbf + plane;
    ushort* kbf    = qbf + plane;
    ushort* vt     = kbf + plane;
    ushort* ctxbf  = xbf;                        // alias (xbf dead after QKV)
    ushort* wqkvt  = vt + plane;                 // [3E][E]
    ushort* wprojt = wqkvt + (size_t)3 * E_ * E_;// [E][E]
    ushort* biasT  = wqkvt;                      // alias (wqkvt dead after QKV)

    const int M = B_ * S_;

    cvtx_kernel<<<dim3(plane / 1024), 256, 0, stream>>>(X, xbf);
    wtrans_kernel<<<dim3(3 * E_ / 64, E_ / 64), 256, 0, stream>>>(Wqkv, wqkvt, E_, 3 * E_);
    wtrans_kernel<<<dim3(E_ / 64, E_ / 64), 256, 0, stream>>>(Wproj, wprojt, E_, E_);

    gemm_mfma_bt<<<dim3(3 * E_ / 128, M / 128), 256, 0, stream>>>(
        xbf, wqkvt, bqkv, M, 3 * E_, E_,
        nullptr, qbf, kout, kbf, vout, 1);

    vtrans_kernel<<<dim3(B_ * H_ * (S_ / 64)), 256, 0, stream>>>(vout, vt);

    // bias pre-pack (writes over dead wqkvt region)
    prep_bias_kernel<<<dim3(528), 256, 0, stream>>>(abias, biasT);

    // flash attention: 512 blocks, 128-row q-tiles, 32 rows/wave
    attn_mfma_kernel<<<dim3(512), 256, 0, stream>>>(
        qbf, kbf, vt, biasT, ctxbf);

    gemm_mfma_bt<<<dim3(E_ / 128, M / 128), 256, 0, stream>>>(
        ctxbf, wprojt, bproj, M, E_, E_,
        out, nullptr, nullptr, nullptr, nullptr, 0);
}

// Round 8
// 226.207 us; speedup vs baseline: 1.1558x; 1.1558x over previous
//
#include <hip/hip_runtime.h>

#define B_ 2
#define S_ 2048
#define E_ 1024
#define H_ 16
#define D_ 64

typedef short  s16x8 __attribute__((ext_vector_type(8)));
typedef float  f32x4 __attribute__((ext_vector_type(4)));
typedef unsigned short u16x4 __attribute__((ext_vector_type(4)));

__device__ __forceinline__ ushort f2bf(float f) {
    union { float f; unsigned u; } x; x.f = f;
    unsigned u = x.u + 0x7fffu + ((x.u >> 16) & 1u);   // RNE
    return (ushort)(u >> 16);
}

__device__ __forceinline__ float fast_exp2(float x) {
    float r; asm("v_exp_f32 %0, %1" : "=v"(r) : "v"(x)); return r;
}

// ---------------------------------------------------------------------------
// Fused preprocessing: cvtx (X fp32->bf16) + both weight transposes.
// blk < 4096: cvtx.  4096..4863: Wqkv transpose.  4864..5119: Wproj transpose.
// (prep_bias stays separate: its output aliases wqkvt, which the QKV GEMM
//  must consume first.)
// ---------------------------------------------------------------------------
__global__ __launch_bounds__(256) void prep_fused_kernel(
    const float* __restrict__ X, ushort* __restrict__ Xbf,
    const float* __restrict__ Wqkv, ushort* __restrict__ Wqkvt,
    const float* __restrict__ Wproj, ushort* __restrict__ Wprojt)
{
    __shared__ float tile[64][65];
    int blk = blockIdx.x;
    int tid = threadIdx.x;
    if (blk < 4096) {                 // ---- cvtx
        int i = (blk * 256 + tid) * 4;
        float4 v = *(const float4*)&X[i];
        u16x4 o;
        o.x = f2bf(v.x); o.y = f2bf(v.y); o.z = f2bf(v.z); o.w = f2bf(v.w);
        *(u16x4*)&Xbf[i] = o;
        return;
    }
    const float* W; ushort* Wt; int Ndim, nb;
    if (blk < 4096 + 768) { blk -= 4096; W = Wqkv;  Wt = Wqkvt;  Ndim = 3 * E_; nb = 48; }
    else                  { blk -= 4864; W = Wproj; Wt = Wprojt; Ndim = E_;     nb = 16; }
    int n0 = (blk % nb) * 64, k0 = (blk / nb) * 64;
    int c = tid & 63;
#pragma unroll
    for (int r = tid >> 6; r < 64; r += 4)
        tile[r][c] = W[(size_t)(k0 + r) * Ndim + n0 + c];
    __syncthreads();
#pragma unroll
    for (int r = tid >> 6; r < 64; r += 4)
        Wt[(size_t)(n0 + r) * E_ + k0 + c] = f2bf(tile[c][r]);
}

// ---------------------------------------------------------------------------
// bias fp32 [S][S] -> biasT bf16, causal-packed tile layout, pre-scaled by
// log2(e).  Tile (qi,ki), ki<=qi, L = qi(qi+1)/2 + ki.  (unchanged from R6)
// ---------------------------------------------------------------------------
__global__ __launch_bounds__(256) void prep_bias_kernel(
    const float* __restrict__ bias, ushort* __restrict__ biasT)
{
    int L = blockIdx.x;
    int qi = (int)((sqrtf(8.0f * (float)L + 1.0f) - 1.0f) * 0.5f);
    while ((qi + 1) * (qi + 2) / 2 <= L) qi++;
    while (qi * (qi + 1) / 2 > L) qi--;
    int ki = L - qi * (qi + 1) / 2;
    int tid = threadIdx.x;
    int w = tid >> 6, quad = (tid >> 4) & 3, l15 = tid & 15;
    const float LOG2E = 1.4426950408889634f;
    s16x8 h0 = (s16x8){0,0,0,0,0,0,0,0}, h1 = (s16x8){0,0,0,0,0,0,0,0};
#pragma unroll
    for (int r = 0; r < 4; r++)
#pragma unroll
        for (int kt = 0; kt < 4; kt++) {
            float v = bias[(size_t)(qi * 64 + w * 16 + quad * 4 + r) * S_
                           + ki * 64 + kt * 16 + l15] * LOG2E;
            ushort u = f2bf(v);
            int idx = r * 4 + kt;
            if (idx < 8) h0[idx] = (short)u; else h1[idx - 8] = (short)u;
        }
    ushort* dst = &biasT[((size_t)L * 256 + tid) * 16];
    *(s16x8*)dst = h0;
    *(s16x8*)(dst + 8) = h1;
}

// ---------------------------------------------------------------------------
// bf16 MFMA GEMM (m97 structure): C[m][n] = sum_k A[m][k]*Bt[n][k] + bias[n]
// ---------------------------------------------------------------------------
__global__ __launch_bounds__(256) void gemm_mfma_bt(
    const ushort* __restrict__ A,    // [M][K] bf16
    const ushort* __restrict__ Bt,   // [N][K] bf16
    const float* __restrict__ bias,  // [N]
    int M, int N, int K,
    float* __restrict__ C0,
    ushort* __restrict__ Qbf, float* __restrict__ Kf32, ushort* __restrict__ Kbf,
    float* __restrict__ Vf32, int mode)
{
    __shared__ ushort As[128 * 32];
    __shared__ ushort Bs[128 * 32];
    int tid = threadIdx.x;
    int wid = tid >> 6, lane = tid & 63;
    int l15 = lane & 15, quad = lane >> 4;
    int wm = wid >> 1, wn = wid & 1;
    int row0 = blockIdx.y * 128, col0 = blockIdx.x * 128;

    int sr = wid * 16 + (lane >> 2);
    int sk = (lane & 3) * 8;

    f32x4 acc[4][4];
#pragma unroll
    for (int mt = 0; mt < 4; mt++)
#pragma unroll
        for (int nt = 0; nt < 4; nt++) acc[mt][nt] = (f32x4){0.f, 0.f, 0.f, 0.f};

    for (int k0 = 0; k0 < K; k0 += 32) {
        __syncthreads();
#pragma unroll
        for (int c = 0; c < 2; c++) {
            int r = c * 64 + sr;
            __builtin_amdgcn_global_load_lds(
                (const __attribute__((address_space(1))) unsigned int*)
                    &A[(size_t)(row0 + r) * K + k0 + sk],
                (__attribute__((address_space(3))) unsigned int*)&As[r * 32 + sk],
                16, 0, 0);
            __builtin_amdgcn_global_load_lds(
                (const __attribute__((address_space(1))) unsigned int*)
                    &Bt[(size_t)(col0 + r) * K + k0 + sk],
                (__attribute__((address_space(3))) unsigned int*)&Bs[r * 32 + sk],
                16, 0, 0);
        }
        __syncthreads();

        s16x8 af[4], bf[4];
#pragma unroll
        for (int mt = 0; mt < 4; mt++)
            af[mt] = *(const s16x8*)&As[(wm * 64 + mt * 16 + l15) * 32 + quad * 8];
#pragma unroll
        for (int nt = 0; nt < 4; nt++)
            bf[nt] = *(const s16x8*)&Bs[(wn * 64 + nt * 16 + l15) * 32 + quad * 8];
#pragma unroll
        for (int mt = 0; mt < 4; mt++)
#pragma unroll
            for (int nt = 0; nt < 4; nt++)
                acc[mt][nt] = __builtin_amdgcn_mfma_f32_16x16x32_bf16(
                    af[mt], bf[nt], acc[mt][nt], 0, 0, 0);
    }

#pragma unroll
    for (int nt = 0; nt < 4; nt++) {
        int n = col0 + wn * 64 + nt * 16 + l15;
        float bv = bias[n];
        if (mode == 1) {
            int seg = n >> 10;
            int nn = n & (E_ - 1);
#pragma unroll
            for (int mt = 0; mt < 4; mt++)
#pragma unroll
                for (int r = 0; r < 4; r++) {
                    int row = row0 + wm * 64 + mt * 16 + quad * 4 + r;
                    float v = acc[mt][nt][r] + bv;
                    size_t idx = (size_t)row * E_ + nn;
                    if (seg == 0)      Qbf[idx] = f2bf(v);
                    else if (seg == 1) { Kf32[idx] = v; Kbf[idx] = f2bf(v); }
                    else               Vf32[idx] = v;
                }
        } else {
#pragma unroll
            for (int mt = 0; mt < 4; mt++)
#pragma unroll
                for (int r = 0; r < 4; r++) {
                    int row = row0 + wm * 64 + mt * 16 + quad * 4 + r;
                    C0[(size_t)row * N + n] = acc[mt][nt][r] + bv;
                }
        }
    }
}

// ---------------------------------------------------------------------------
// V transpose: fp32 V [b*S+s][h*64+d] -> bf16 Vt [(b*H+h)*64+d][s], with
// IN-TILE KEY PERMUTATION: position j within each 64-key tile holds actual
// key pi(j) = (j&3)*16 + (j>>2).  This matches the attn kernel's new Ps
// layout (col = l15*4 + kt), making the PV dot-product key-order invariant.
// ---------------------------------------------------------------------------
__global__ __launch_bounds__(256) void vtrans_kernel(
    const float* __restrict__ V, ushort* __restrict__ Vt)
{
    __shared__ float tile[64][65];
    int blk = blockIdx.x;
    int s0 = (blk & 31) * 64;
    int bh = blk >> 5;
    int b = bh >> 4, h = bh & 15;
    int tid = threadIdx.x;
    int d = tid & 63;
#pragma unroll
    for (int i = tid >> 6; i < 64; i += 4)
        tile[i][d] = V[((size_t)(b * S_ + s0 + i)) * E_ + h * 64 + d];
    __syncthreads();
    int lane = tid & 63, w = tid >> 6;
    int src = ((lane & 3) * 16) + (lane >> 2);   // pi(lane)
#pragma unroll
    for (int dd = w; dd < 64; dd += 4)
        Vt[((size_t)(bh * 64 + dd)) * S_ + s0 + lane] = f2bf(tile[src][dd]);
}

// ---------------------------------------------------------------------------
// MFMA flash attention, fixed-reference softmax — round 13.
// Base = R6 (proven 51us: 512 uniform paired blocks, 4 waves, K/V XOR-swizzle
// LDS staging, biasT bf16 + exp2-direct, 2 barriers/tile, reg prefetch).
// R7's 128-row tiles regressed (tail starvation + longer serial chain) and is
// fully reverted.  New in this round — Ps layout only:
//   Ps col = l15*4 + kt (kt fastest).  Each lane's 4 P values pack into ONE
//   ds_write_b64 via 2x v_cvt_pk_bf16_f32 (was 16 ds_write_b16 + 16 manual
//   f2bf per wave per tile).  PV A-frag reads become plain b128 at quad*8.
//   Correctness: V's key dim is permuted identically (vtrans pi), so
//   sum_j P[row][pi(j)] V[pi(j)][d] == sum_k P[row][k] V[k][d].
// Bank analysis: b64 writes 2-way (free, m136); b128 reads same 8-lane
// residue distribution as R6's measured-good swizzle.
// ---------------------------------------------------------------------------
__global__ __launch_bounds__(256) void attn_mfma_kernel(
    const ushort* __restrict__ Qbf,   // [B*S, E] bf16
    const ushort* __restrict__ Kbf,   // [B*S, E] bf16
    const ushort* __restrict__ Vt,    // [(b*H+h)*64+d][s] bf16, key-permuted
    const ushort* __restrict__ biasT, // causal-packed bf16 tiles (prep_bias)
    ushort* __restrict__ Ctx)         // [B*S, E] bf16
{
    __shared__ ushort Ks[64][64];
    __shared__ ushort Vs[64][64];
    __shared__ ushort Ps[4][16][72];

    int blk = blockIdx.x;
    int bh = blk & 31;               // XCD = bh%8 -> K/V L2 locality
    int pr = blk >> 5;               // 0..15
    int b = bh >> 4, h = bh & 15;
    int tid = threadIdx.x;
    int wid = tid >> 6, lane = tid & 63;
    int l15 = lane & 15, quad = lane >> 4;

    int skey = tid >> 2;
    int scol = (tid & 3) * 16;       // ushort col of this thread's 16B pair
    int sc0 = ((((tid & 3) * 2) ^ (skey & 7)) * 8);
    int sc1 = sc0 ^ 8;
    const float scale_l2e = 0.18033688011112042f;   // 0.125 * log2(e)

    const size_t krow = (size_t)(b * S_ + skey) * E_ + h * 64 + scol; // + j0*E_
    const size_t vrow = (size_t)(bh * 64 + skey) * S_ + scol;        // + j0
    int rc0 = (quad ^ (l15 & 7)) * 8;

    for (int half = 0; half < 2; half++) {
        int qt = half ? pr : (31 - pr);
        int q0w = qt * 64 + wid * 16;

        // Q fragments (A-layout)
        const size_t qbase = ((size_t)(b * S_ + q0w + l15)) * E_ + h * 64 + quad * 8;
        s16x8 qa0 = *(const s16x8*)&Qbf[qbase];
        s16x8 qa1 = *(const s16x8*)&Qbf[qbase + 32];

        f32x4 o[4];
#pragma unroll
        for (int dt = 0; dt < 4; dt++) o[dt] = (f32x4){0.f, 0.f, 0.f, 0.f};
        float lsum[4];
#pragma unroll
        for (int r = 0; r < 4; r++) lsum[r] = 0.f;

        // ---- preload tile 0 into registers
        float4 kr0 = ((const float4*)&Kbf[krow])[0];
        float4 kr1 = ((const float4*)&Kbf[krow])[1];
        float4 vr0 = ((const float4*)&Vt[vrow])[0];
        float4 vr1 = ((const float4*)&Vt[vrow])[1];
        const ushort* bt = &biasT[((size_t)(qt * (qt + 1) / 2) * 256 + tid) * 16];
        s16x8 bn0 = *(const s16x8*)bt;
        s16x8 bn1 = *(const s16x8*)(bt + 8);

        for (int t = 0; t <= qt; t++) {
            int j0 = t * 64;
            __syncthreads();          // prior compute done; LDS free
            *(float4*)&Ks[skey][sc0] = kr0;
            *(float4*)&Ks[skey][sc1] = kr1;
            *(float4*)&Vs[skey][sc0] = vr0;
            *(float4*)&Vs[skey][sc1] = vr1;
            s16x8 b0 = bn0, b1 = bn1;
            __syncthreads();

            // ---- prefetch tile t+1 (registers only; hides under compute)
            if (t < qt) {
                int j1 = j0 + 64;
                kr0 = ((const float4*)&Kbf[krow + (size_t)j1 * E_])[0];
                kr1 = ((const float4*)&Kbf[krow + (size_t)j1 * E_])[1];
                vr0 = ((const float4*)&Vt[vrow + j1])[0];
                vr1 = ((const float4*)&Vt[vrow + j1])[1];
                const ushort* btn = bt + (size_t)(t + 1) * 4096;
                bn0 = *(const s16x8*)btn;
                bn1 = *(const s16x8*)(btn + 8);
            }

            // ---- S = Q K^T : rows=q(quad*4+r), cols=key(kt*16+l15)
            f32x4 s[4];
#pragma unroll
            for (int kt = 0; kt < 4; kt++) {
                s16x8 kb0 = *(const s16x8*)&Ks[kt * 16 + l15][rc0];
                s16x8 kb1 = *(const s16x8*)&Ks[kt * 16 + l15][rc0 ^ 32];
                f32x4 acc = (f32x4){0.f, 0.f, 0.f, 0.f};
                acc = __builtin_amdgcn_mfma_f32_16x16x32_bf16(qa0, kb0, acc, 0, 0, 0);
                acc = __builtin_amdgcn_mfma_f32_16x16x32_bf16(qa1, kb1, acc, 0, 0, 0);
                s[kt] = acc;
            }

            // ---- p = exp2(s*scale + biasT); causal mask; packed b64 Ps write
            bool diag = (t == qt);
#pragma unroll
            for (int r = 0; r < 4; r++) {
                int row = q0w + quad * 4 + r;
                float pv[4];
#pragma unroll
                for (int kt = 0; kt < 4; kt++) {
                    int j = j0 + kt * 16 + l15;
                    int idx = r * 4 + kt;
                    ushort ub = (ushort)((idx < 8) ? b0[idx] : b1[idx - 8]);
                    union { unsigned u; float f; } bc; bc.u = ((unsigned)ub) << 16;
                    float v = fmaf(s[kt][r], scale_l2e, bc.f);
                    float p = (diag && j > row) ? 0.f : fast_exp2(v);
                    lsum[r] += p;
                    pv[kt] = p;
                }
                unsigned w0, w1;
                asm("v_cvt_pk_bf16_f32 %0, %1, %2" : "=v"(w0) : "v"(pv[0]), "v"(pv[1]));
                asm("v_cvt_pk_bf16_f32 %0, %1, %2" : "=v"(w1) : "v"(pv[2]), "v"(pv[3]));
                uint2 wv; wv.x = w0; wv.y = w1;
                *(uint2*)&Ps[wid][quad * 4 + r][l15 * 4] = wv;
            }

            // ---- O += P V  (Ps wave-private: no barrier; permuted key dim)
            s16x8 pa0 = *(const s16x8*)&Ps[wid][l15][quad * 8];
            s16x8 pa1 = *(const s16x8*)&Ps[wid][l15][32 + quad * 8];
#pragma unroll
            for (int dt = 0; dt < 4; dt++) {
                s16x8 vb0 = *(const s16x8*)&Vs[dt * 16 + l15][rc0];
                s16x8 vb1 = *(const s16x8*)&Vs[dt * 16 + l15][rc0 ^ 32];
                o[dt] = __builtin_amdgcn_mfma_f32_16x16x32_bf16(pa0, vb0, o[dt], 0, 0, 0);
                o[dt] = __builtin_amdgcn_mfma_f32_16x16x32_bf16(pa1, vb1, o[dt], 0, 0, 0);
            }
        }

        // ---- single final row-sum reduction
        float inv_l[4];
#pragma unroll
        for (int r = 0; r < 4; r++) {
            float l = lsum[r];
            l += __shfl_xor(l, 1);
            l += __shfl_xor(l, 2);
            l += __shfl_xor(l, 4);
            l += __shfl_xor(l, 8);
            inv_l[r] = 1.f / l;
        }

#pragma unroll
        for (int dt = 0; dt < 4; dt++) {
#pragma unroll
            for (int r = 0; r < 4; r++) {
                int row = q0w + quad * 4 + r;
                Ctx[((size_t)(b * S_ + row)) * E_ + h * 64 + dt * 16 + l15] =
                    f2bf(o[dt][r] * inv_l[r]);
            }
        }
    }
}

// ---------------------------------------------------------------------------
extern "C" void kernel_launch(void* const* d_in, const int* in_sizes, int n_in,
                              void* d_out, int out_size, void* d_ws, size_t ws_size,
                              hipStream_t stream) {
    const float* X     = (const float*)d_in[0];
    const float* abias = (const float*)d_in[1];
    const float* Wqkv  = (const float*)d_in[2];
    const float* bqkv  = (const float*)d_in[3];
    const float* Wproj = (const float*)d_in[4];
    const float* bproj = (const float*)d_in[5];

    const size_t plane = (size_t)B_ * S_ * E_;   // 4,194,304
    float* out  = (float*)d_out;
    float* kout = out + plane;                   // cache_key (fp32 output)
    float* vout = kout + plane;                  // cache_value (fp32 output)

    // workspace: 4 bf16 planes + weights = 42 MB (proven footprint).
    // ctxbf ALIASES xbf (X's bf16 copy is dead after the QKV GEMM).
    // biasT ALIASES wqkvt (Wqkv^T dead after the QKV GEMM; 4.3MB <= 6MB).
    ushort* xbf    = (ushort*)d_ws;
    ushort* qbf    = xbf + plane;
    ushort* kbf    = qbf + plane;
    ushort* vt     = kbf + plane;
    ushort* ctxbf  = xbf;                        // alias (see above)
    ushort* wqkvt  = vt + plane;                 // [3E][E]
    ushort* wprojt = wqkvt + (size_t)3 * E_ * E_;// [E][E]
    ushort* biasT  = wqkvt;                      // alias (see above)

    const int M = B_ * S_;

    // fused: cvtx (4096 blocks) + Wqkv^T (768) + Wproj^T (256)
    prep_fused_kernel<<<dim3(5120), 256, 0, stream>>>(
        X, xbf, Wqkv, wqkvt, Wproj, wprojt);

    gemm_mfma_bt<<<dim3(3 * E_ / 128, M / 128), 256, 0, stream>>>(
        xbf, wqkvt, bqkv, M, 3 * E_, E_,
        nullptr, qbf, kout, kbf, vout, 1);

    vtrans_kernel<<<dim3(B_ * H_ * (S_ / 64)), 256, 0, stream>>>(vout, vt);

    // bias pre-pack (writes over dead wqkvt region)
    prep_bias_kernel<<<dim3(528), 256, 0, stream>>>(abias, biasT);

    // flash attention: 512 paired blocks; XCD = bh%8 for K/V L2 locality
    attn_mfma_kernel<<<dim3(B_ * H_ * 16), 256, 0, stream>>>(
        qbf, kbf, vt, biasT, ctxbf);

    gemm_mfma_bt<<<dim3(E_ / 128, M / 128), 256, 0, stream>>>(
        ctxbf, wprojt, bproj, M, E_, E_,
        out, nullptr, nullptr, nullptr, nullptr, 0);
}

// Round 9
// 214.037 us; speedup vs baseline: 1.2215x; 1.0569x over previous
//
#include <hip/hip_runtime.h>

#define B_ 2
#define S_ 2048
#define E_ 1024
#define H_ 16
#define D_ 64

typedef short  s16x8 __attribute__((ext_vector_type(8)));
typedef float  f32x4 __attribute__((ext_vector_type(4)));
typedef unsigned short u16x4 __attribute__((ext_vector_type(4)));

__device__ __forceinline__ ushort f2bf(float f) {
    union { float f; unsigned u; } x; x.f = f;
    unsigned u = x.u + 0x7fffu + ((x.u >> 16) & 1u);   // RNE
    return (ushort)(u >> 16);
}

__device__ __forceinline__ float fast_exp2(float x) {
    float r; asm("v_exp_f32 %0, %1" : "=v"(r) : "v"(x)); return r;
}

// ---------------------------------------------------------------------------
// Fused preprocessing: cvtx (X fp32->bf16) + both weight transposes.
// blk < 4096: cvtx.  4096..4863: Wqkv transpose.  4864..5119: Wproj transpose.
// ---------------------------------------------------------------------------
__global__ __launch_bounds__(256) void prep_fused_kernel(
    const float* __restrict__ X, ushort* __restrict__ Xbf,
    const float* __restrict__ Wqkv, ushort* __restrict__ Wqkvt,
    const float* __restrict__ Wproj, ushort* __restrict__ Wprojt)
{
    __shared__ float tile[64][65];
    int blk = blockIdx.x;
    int tid = threadIdx.x;
    if (blk < 4096) {                 // ---- cvtx
        int i = (blk * 256 + tid) * 4;
        float4 v = *(const float4*)&X[i];
        u16x4 o;
        o.x = f2bf(v.x); o.y = f2bf(v.y); o.z = f2bf(v.z); o.w = f2bf(v.w);
        *(u16x4*)&Xbf[i] = o;
        return;
    }
    const float* W; ushort* Wt; int Ndim, nb;
    if (blk < 4096 + 768) { blk -= 4096; W = Wqkv;  Wt = Wqkvt;  Ndim = 3 * E_; nb = 48; }
    else                  { blk -= 4864; W = Wproj; Wt = Wprojt; Ndim = E_;     nb = 16; }
    int n0 = (blk % nb) * 64, k0 = (blk / nb) * 64;
    int c = tid & 63;
#pragma unroll
    for (int r = tid >> 6; r < 64; r += 4)
        tile[r][c] = W[(size_t)(k0 + r) * Ndim + n0 + c];
    __syncthreads();
#pragma unroll
    for (int r = tid >> 6; r < 64; r += 4)
        Wt[(size_t)(n0 + r) * E_ + k0 + c] = f2bf(tile[c][r]);
}

// ---------------------------------------------------------------------------
// bias fp32 [S][S] -> biasT bf16, causal-packed tile layout, pre-scaled by
// log2(e).  Tile (qi,ki), ki<=qi, L = qi(qi+1)/2 + ki.  (unchanged)
// ---------------------------------------------------------------------------
__global__ __launch_bounds__(256) void prep_bias_kernel(
    const float* __restrict__ bias, ushort* __restrict__ biasT)
{
    int L = blockIdx.x;
    int qi = (int)((sqrtf(8.0f * (float)L + 1.0f) - 1.0f) * 0.5f);
    while ((qi + 1) * (qi + 2) / 2 <= L) qi++;
    while (qi * (qi + 1) / 2 > L) qi--;
    int ki = L - qi * (qi + 1) / 2;
    int tid = threadIdx.x;
    int w = tid >> 6, quad = (tid >> 4) & 3, l15 = tid & 15;
    const float LOG2E = 1.4426950408889634f;
    s16x8 h0 = (s16x8){0,0,0,0,0,0,0,0}, h1 = (s16x8){0,0,0,0,0,0,0,0};
#pragma unroll
    for (int r = 0; r < 4; r++)
#pragma unroll
        for (int kt = 0; kt < 4; kt++) {
            float v = bias[(size_t)(qi * 64 + w * 16 + quad * 4 + r) * S_
                           + ki * 64 + kt * 16 + l15] * LOG2E;
            ushort u = f2bf(v);
            int idx = r * 4 + kt;
            if (idx < 8) h0[idx] = (short)u; else h1[idx - 8] = (short)u;
        }
    ushort* dst = &biasT[((size_t)L * 256 + tid) * 16];
    *(s16x8*)dst = h0;
    *(s16x8*)(dst + 8) = h1;
}

// ---------------------------------------------------------------------------
// bf16 MFMA GEMM — round 14: BK 32->64 + XOR-swizzled LDS (via pre-swizzled
// GLOBAL source; LDS dest stays linear as global_load_lds requires).
// R8 counters for this kernel: MfmaUtil 12.6, VALUBusy 22.5, occ 31.7, bank
// conflicts 3.1M -> barrier/drain-bound K-loop (16 MFMA per 2-barrier pair).
// Changes:
//  - BK=64: 32 MFMAs per barrier pair (16 K-steps at K=1024). LDS 32KB.
//  - layout As/Bs[r][64] with physical 16B-chunk p holding logical chunk
//    p^(r&7).  Staging: lane fetches global chunk (lane&7)^(lane>>3) so the
//    linear LDS write lands swizzled.  Frag reads use chunk (kk*4+quad)^
//    (l15&7): per quarter-wave phase 2 lanes/bank = conflict-free (the old
//    BK=32 layout was 8 lanes per 4-bank group per phase -> the 3.1M).
// Epilogue (mode 0/1) unchanged.
// ---------------------------------------------------------------------------
__global__ __launch_bounds__(256) void gemm_mfma_bt(
    const ushort* __restrict__ A,    // [M][K] bf16
    const ushort* __restrict__ Bt,   // [N][K] bf16
    const float* __restrict__ bias,  // [N]
    int M, int N, int K,
    float* __restrict__ C0,
    ushort* __restrict__ Qbf, float* __restrict__ Kf32, ushort* __restrict__ Kbf,
    float* __restrict__ Vf32, int mode)
{
    __shared__ ushort As[128 * 64];
    __shared__ ushort Bs[128 * 64];
    int tid = threadIdx.x;
    int wid = tid >> 6, lane = tid & 63;
    int l15 = lane & 15, quad = lane >> 4;
    int wm = wid >> 1, wn = wid & 1;
    int row0 = blockIdx.y * 128, col0 = blockIdx.x * 128;

    int srow = tid >> 3;                         // 0..31 (row within round)
    int pk = (tid & 7) * 8;                      // physical chunk (LDS, linear)
    int sk = (((tid & 7) ^ (srow & 7)) * 8);     // logical chunk (global src)

    f32x4 acc[4][4];
#pragma unroll
    for (int mt = 0; mt < 4; mt++)
#pragma unroll
        for (int nt = 0; nt < 4; nt++) acc[mt][nt] = (f32x4){0.f, 0.f, 0.f, 0.f};

    for (int k0 = 0; k0 < K; k0 += 64) {
        __syncthreads();
#pragma unroll
        for (int c = 0; c < 4; c++) {
            int r = c * 32 + srow;
            __builtin_amdgcn_global_load_lds(
                (const __attribute__((address_space(1))) unsigned int*)
                    &A[(size_t)(row0 + r) * K + k0 + sk],
                (__attribute__((address_space(3))) unsigned int*)&As[r * 64 + pk],
                16, 0, 0);
            __builtin_amdgcn_global_load_lds(
                (const __attribute__((address_space(1))) unsigned int*)
                    &Bt[(size_t)(col0 + r) * K + k0 + sk],
                (__attribute__((address_space(3))) unsigned int*)&Bs[r * 64 + pk],
                16, 0, 0);
        }
        __syncthreads();

#pragma unroll
        for (int kk = 0; kk < 2; kk++) {
            int xc = (((kk * 4 + quad) ^ (l15 & 7)) * 8);
            s16x8 af[4], bf[4];
#pragma unroll
            for (int mt = 0; mt < 4; mt++)
                af[mt] = *(const s16x8*)&As[(wm * 64 + mt * 16 + l15) * 64 + xc];
#pragma unroll
            for (int nt = 0; nt < 4; nt++)
                bf[nt] = *(const s16x8*)&Bs[(wn * 64 + nt * 16 + l15) * 64 + xc];
#pragma unroll
            for (int mt = 0; mt < 4; mt++)
#pragma unroll
                for (int nt = 0; nt < 4; nt++)
                    acc[mt][nt] = __builtin_amdgcn_mfma_f32_16x16x32_bf16(
                        af[mt], bf[nt], acc[mt][nt], 0, 0, 0);
        }
    }

#pragma unroll
    for (int nt = 0; nt < 4; nt++) {
        int n = col0 + wn * 64 + nt * 16 + l15;
        float bv = bias[n];
        if (mode == 1) {
            int seg = n >> 10;
            int nn = n & (E_ - 1);
#pragma unroll
            for (int mt = 0; mt < 4; mt++)
#pragma unroll
                for (int r = 0; r < 4; r++) {
                    int row = row0 + wm * 64 + mt * 16 + quad * 4 + r;
                    float v = acc[mt][nt][r] + bv;
                    size_t idx = (size_t)row * E_ + nn;
                    if (seg == 0)      Qbf[idx] = f2bf(v);
                    else if (seg == 1) { Kf32[idx] = v; Kbf[idx] = f2bf(v); }
                    else               Vf32[idx] = v;
                }
        } else {
#pragma unroll
            for (int mt = 0; mt < 4; mt++)
#pragma unroll
                for (int r = 0; r < 4; r++) {
                    int row = row0 + wm * 64 + mt * 16 + quad * 4 + r;
                    C0[(size_t)row * N + n] = acc[mt][nt][r] + bv;
                }
        }
    }
}

// ---------------------------------------------------------------------------
// V transpose: fp32 V [b*S+s][h*64+d] -> bf16 Vt [(b*H+h)*64+d][s], with
// IN-TILE KEY PERMUTATION pi(j) = (j&3)*16 + (j>>2) (matches attn Ps layout).
// ---------------------------------------------------------------------------
__global__ __launch_bounds__(256) void vtrans_kernel(
    const float* __restrict__ V, ushort* __restrict__ Vt)
{
    __shared__ float tile[64][65];
    int blk = blockIdx.x;
    int s0 = (blk & 31) * 64;
    int bh = blk >> 5;
    int b = bh >> 4, h = bh & 15;
    int tid = threadIdx.x;
    int d = tid & 63;
#pragma unroll
    for (int i = tid >> 6; i < 64; i += 4)
        tile[i][d] = V[((size_t)(b * S_ + s0 + i)) * E_ + h * 64 + d];
    __syncthreads();
    int lane = tid & 63, w = tid >> 6;
    int src = ((lane & 3) * 16) + (lane >> 2);   // pi(lane)
#pragma unroll
    for (int dd = w; dd < 64; dd += 4)
        Vt[((size_t)(bh * 64 + dd)) * S_ + s0 + lane] = f2bf(tile[src][dd]);
}

// ---------------------------------------------------------------------------
// MFMA flash attention, fixed-reference softmax — unchanged from round 13
// (512 uniform paired blocks, K/V XOR-swizzle, biasT+exp2, packed b64 Ps).
// ---------------------------------------------------------------------------
__global__ __launch_bounds__(256) void attn_mfma_kernel(
    const ushort* __restrict__ Qbf,   // [B*S, E] bf16
    const ushort* __restrict__ Kbf,   // [B*S, E] bf16
    const ushort* __restrict__ Vt,    // [(b*H+h)*64+d][s] bf16, key-permuted
    const ushort* __restrict__ biasT, // causal-packed bf16 tiles (prep_bias)
    ushort* __restrict__ Ctx)         // [B*S, E] bf16
{
    __shared__ ushort Ks[64][64];
    __shared__ ushort Vs[64][64];
    __shared__ ushort Ps[4][16][72];

    int blk = blockIdx.x;
    int bh = blk & 31;               // XCD = bh%8 -> K/V L2 locality
    int pr = blk >> 5;               // 0..15
    int b = bh >> 4, h = bh & 15;
    int tid = threadIdx.x;
    int wid = tid >> 6, lane = tid & 63;
    int l15 = lane & 15, quad = lane >> 4;

    int skey = tid >> 2;
    int scol = (tid & 3) * 16;       // ushort col of this thread's 16B pair
    int sc0 = ((((tid & 3) * 2) ^ (skey & 7)) * 8);
    int sc1 = sc0 ^ 8;
    const float scale_l2e = 0.18033688011112042f;   // 0.125 * log2(e)

    const size_t krow = (size_t)(b * S_ + skey) * E_ + h * 64 + scol; // + j0*E_
    const size_t vrow = (size_t)(bh * 64 + skey) * S_ + scol;        // + j0
    int rc0 = (quad ^ (l15 & 7)) * 8;

    for (int half = 0; half < 2; half++) {
        int qt = half ? pr : (31 - pr);
        int q0w = qt * 64 + wid * 16;

        // Q fragments (A-layout)
        const size_t qbase = ((size_t)(b * S_ + q0w + l15)) * E_ + h * 64 + quad * 8;
        s16x8 qa0 = *(const s16x8*)&Qbf[qbase];
        s16x8 qa1 = *(const s16x8*)&Qbf[qbase + 32];

        f32x4 o[4];
#pragma unroll
        for (int dt = 0; dt < 4; dt++) o[dt] = (f32x4){0.f, 0.f, 0.f, 0.f};
        float lsum[4];
#pragma unroll
        for (int r = 0; r < 4; r++) lsum[r] = 0.f;

        // ---- preload tile 0 into registers
        float4 kr0 = ((const float4*)&Kbf[krow])[0];
        float4 kr1 = ((const float4*)&Kbf[krow])[1];
        float4 vr0 = ((const float4*)&Vt[vrow])[0];
        float4 vr1 = ((const float4*)&Vt[vrow])[1];
        const ushort* bt = &biasT[((size_t)(qt * (qt + 1) / 2) * 256 + tid) * 16];
        s16x8 bn0 = *(const s16x8*)bt;
        s16x8 bn1 = *(const s16x8*)(bt + 8);

        for (int t = 0; t <= qt; t++) {
            int j0 = t * 64;
            __syncthreads();          // prior compute done; LDS free
            *(float4*)&Ks[skey][sc0] = kr0;
            *(float4*)&Ks[skey][sc1] = kr1;
            *(float4*)&Vs[skey][sc0] = vr0;
            *(float4*)&Vs[skey][sc1] = vr1;
            s16x8 b0 = bn0, b1 = bn1;
            __syncthreads();

            // ---- prefetch tile t+1 (registers only; hides under compute)
            if (t < qt) {
                int j1 = j0 + 64;
                kr0 = ((const float4*)&Kbf[krow + (size_t)j1 * E_])[0];
                kr1 = ((const float4*)&Kbf[krow + (size_t)j1 * E_])[1];
                vr0 = ((const float4*)&Vt[vrow + j1])[0];
                vr1 = ((const float4*)&Vt[vrow + j1])[1];
                const ushort* btn = bt + (size_t)(t + 1) * 4096;
                bn0 = *(const s16x8*)btn;
                bn1 = *(const s16x8*)(btn + 8);
            }

            // ---- S = Q K^T : rows=q(quad*4+r), cols=key(kt*16+l15)
            f32x4 s[4];
#pragma unroll
            for (int kt = 0; kt < 4; kt++) {
                s16x8 kb0 = *(const s16x8*)&Ks[kt * 16 + l15][rc0];
                s16x8 kb1 = *(const s16x8*)&Ks[kt * 16 + l15][rc0 ^ 32];
                f32x4 acc = (f32x4){0.f, 0.f, 0.f, 0.f};
                acc = __builtin_amdgcn_mfma_f32_16x16x32_bf16(qa0, kb0, acc, 0, 0, 0);
                acc = __builtin_amdgcn_mfma_f32_16x16x32_bf16(qa1, kb1, acc, 0, 0, 0);
                s[kt] = acc;
            }

            // ---- p = exp2(s*scale + biasT); causal mask; packed b64 Ps write
            bool diag = (t == qt);
#pragma unroll
            for (int r = 0; r < 4; r++) {
                int row = q0w + quad * 4 + r;
                float pv[4];
#pragma unroll
                for (int kt = 0; kt < 4; kt++) {
                    int j = j0 + kt * 16 + l15;
                    int idx = r * 4 + kt;
                    ushort ub = (ushort)((idx < 8) ? b0[idx] : b1[idx - 8]);
                    union { unsigned u; float f; } bc; bc.u = ((unsigned)ub) << 16;
                    float v = fmaf(s[kt][r], scale_l2e, bc.f);
                    float p = (diag && j > row) ? 0.f : fast_exp2(v);
                    lsum[r] += p;
                    pv[kt] = p;
                }
                unsigned w0, w1;
                asm("v_cvt_pk_bf16_f32 %0, %1, %2" : "=v"(w0) : "v"(pv[0]), "v"(pv[1]));
                asm("v_cvt_pk_bf16_f32 %0, %1, %2" : "=v"(w1) : "v"(pv[2]), "v"(pv[3]));
                uint2 wv; wv.x = w0; wv.y = w1;
                *(uint2*)&Ps[wid][quad * 4 + r][l15 * 4] = wv;
            }

            // ---- O += P V  (Ps wave-private: no barrier; permuted key dim)
            s16x8 pa0 = *(const s16x8*)&Ps[wid][l15][quad * 8];
            s16x8 pa1 = *(const s16x8*)&Ps[wid][l15][32 + quad * 8];
#pragma unroll
            for (int dt = 0; dt < 4; dt++) {
                s16x8 vb0 = *(const s16x8*)&Vs[dt * 16 + l15][rc0];
                s16x8 vb1 = *(const s16x8*)&Vs[dt * 16 + l15][rc0 ^ 32];
                o[dt] = __builtin_amdgcn_mfma_f32_16x16x32_bf16(pa0, vb0, o[dt], 0, 0, 0);
                o[dt] = __builtin_amdgcn_mfma_f32_16x16x32_bf16(pa1, vb1, o[dt], 0, 0, 0);
            }
        }

        // ---- single final row-sum reduction
        float inv_l[4];
#pragma unroll
        for (int r = 0; r < 4; r++) {
            float l = lsum[r];
            l += __shfl_xor(l, 1);
            l += __shfl_xor(l, 2);
            l += __shfl_xor(l, 4);
            l += __shfl_xor(l, 8);
            inv_l[r] = 1.f / l;
        }

#pragma unroll
        for (int dt = 0; dt < 4; dt++) {
#pragma unroll
            for (int r = 0; r < 4; r++) {
                int row = q0w + quad * 4 + r;
                Ctx[((size_t)(b * S_ + row)) * E_ + h * 64 + dt * 16 + l15] =
                    f2bf(o[dt][r] * inv_l[r]);
            }
        }
    }
}

// ---------------------------------------------------------------------------
extern "C" void kernel_launch(void* const* d_in, const int* in_sizes, int n_in,
                              void* d_out, int out_size, void* d_ws, size_t ws_size,
                              hipStream_t stream) {
    const float* X     = (const float*)d_in[0];
    const float* abias = (const float*)d_in[1];
    const float* Wqkv  = (const float*)d_in[2];
    const float* bqkv  = (const float*)d_in[3];
    const float* Wproj = (const float*)d_in[4];
    const float* bproj = (const float*)d_in[5];

    const size_t plane = (size_t)B_ * S_ * E_;   // 4,194,304
    float* out  = (float*)d_out;
    float* kout = out + plane;                   // cache_key (fp32 output)
    float* vout = kout + plane;                  // cache_value (fp32 output)

    // workspace: 4 bf16 planes + weights = 42 MB (proven footprint).
    // ctxbf ALIASES xbf (X's bf16 copy is dead after the QKV GEMM).
    // biasT ALIASES wqkvt (Wqkv^T dead after the QKV GEMM; 4.3MB <= 6MB).
    ushort* xbf    = (ushort*)d_ws;
    ushort* qbf    = xbf + plane;
    ushort* kbf    = qbf + plane;
    ushort* vt     = kbf + plane;
    ushort* ctxbf  = xbf;                        // alias (see above)
    ushort* wqkvt  = vt + plane;                 // [3E][E]
    ushort* wprojt = wqkvt + (size_t)3 * E_ * E_;// [E][E]
    ushort* biasT  = wqkvt;                      // alias (see above)

    const int M = B_ * S_;

    // fused: cvtx (4096 blocks) + Wqkv^T (768) + Wproj^T (256)
    prep_fused_kernel<<<dim3(5120), 256, 0, stream>>>(
        X, xbf, Wqkv, wqkvt, Wproj, wprojt);

    gemm_mfma_bt<<<dim3(3 * E_ / 128, M / 128), 256, 0, stream>>>(
        xbf, wqkvt, bqkv, M, 3 * E_, E_,
        nullptr, qbf, kout, kbf, vout, 1);

    vtrans_kernel<<<dim3(B_ * H_ * (S_ / 64)), 256, 0, stream>>>(vout, vt);

    // bias pre-pack (writes over dead wqkvt region)
    prep_bias_kernel<<<dim3(528), 256, 0, stream>>>(abias, biasT);

    // flash attention: 512 paired blocks; XCD = bh%8 for K/V L2 locality
    attn_mfma_kernel<<<dim3(B_ * H_ * 16), 256, 0, stream>>>(
        qbf, kbf, vt, biasT, ctxbf);

    gemm_mfma_bt<<<dim3(E_ / 128, M / 128), 256, 0, stream>>>(
        ctxbf, wprojt, bproj, M, E_, E_,
        out, nullptr, nullptr, nullptr, nullptr, 0);
}

// Round 10
// 211.781 us; speedup vs baseline: 1.2345x; 1.0107x over previous
//
#include <hip/hip_runtime.h>

#define B_ 2
#define S_ 2048
#define E_ 1024
#define H_ 16
#define D_ 64

typedef short  s16x8 __attribute__((ext_vector_type(8)));
typedef float  f32x4 __attribute__((ext_vector_type(4)));
typedef unsigned short u16x4 __attribute__((ext_vector_type(4)));

__device__ __forceinline__ ushort f2bf(float f) {
    union { float f; unsigned u; } x; x.f = f;
    unsigned u = x.u + 0x7fffu + ((x.u >> 16) & 1u);   // RNE
    return (ushort)(u >> 16);
}

__device__ __forceinline__ float fast_exp2(float x) {
    float r; asm("v_exp_f32 %0, %1" : "=v"(r) : "v"(x)); return r;
}

// ---------------------------------------------------------------------------
// Fused preprocessing: cvtx (X fp32->bf16) + both weight transposes.
// blk < 4096: cvtx.  4096..4863: Wqkv transpose.  4864..5119: Wproj transpose.
// ---------------------------------------------------------------------------
__global__ __launch_bounds__(256) void prep_fused_kernel(
    const float* __restrict__ X, ushort* __restrict__ Xbf,
    const float* __restrict__ Wqkv, ushort* __restrict__ Wqkvt,
    const float* __restrict__ Wproj, ushort* __restrict__ Wprojt)
{
    __shared__ float tile[64][65];
    int blk = blockIdx.x;
    int tid = threadIdx.x;
    if (blk < 4096) {                 // ---- cvtx
        int i = (blk * 256 + tid) * 4;
        float4 v = *(const float4*)&X[i];
        u16x4 o;
        o.x = f2bf(v.x); o.y = f2bf(v.y); o.z = f2bf(v.z); o.w = f2bf(v.w);
        *(u16x4*)&Xbf[i] = o;
        return;
    }
    const float* W; ushort* Wt; int Ndim, nb;
    if (blk < 4096 + 768) { blk -= 4096; W = Wqkv;  Wt = Wqkvt;  Ndim = 3 * E_; nb = 48; }
    else                  { blk -= 4864; W = Wproj; Wt = Wprojt; Ndim = E_;     nb = 16; }
    int n0 = (blk % nb) * 64, k0 = (blk / nb) * 64;
    int c = tid & 63;
#pragma unroll
    for (int r = tid >> 6; r < 64; r += 4)
        tile[r][c] = W[(size_t)(k0 + r) * Ndim + n0 + c];
    __syncthreads();
#pragma unroll
    for (int r = tid >> 6; r < 64; r += 4)
        Wt[(size_t)(n0 + r) * E_ + k0 + c] = f2bf(tile[c][r]);
}

// ---------------------------------------------------------------------------
// Fused post-QKV prep: V transpose (blocks 0..1023) + bias pre-pack
// (blocks 1024..1551).  Both depend only on the QKV GEMM's outputs; fusing
// saves one launch gap.
//  vtrans: fp32 V [b*S+s][h*64+d] -> bf16 Vt [(b*H+h)*64+d][s], with the
//  IN-TILE KEY PERMUTATION pi(j) = (j&3)*16 + (j>>2) (matches attn Ps layout).
//  prep_bias: fp32 bias [S][S] -> causal-packed bf16 tiles, pre-scaled by
//  log2(e), 16 contiguous values per consumer thread.
// ---------------------------------------------------------------------------
__global__ __launch_bounds__(256) void post_qkv_kernel(
    const float* __restrict__ V, ushort* __restrict__ Vt,
    const float* __restrict__ bias, ushort* __restrict__ biasT)
{
    __shared__ float tile[64][65];
    int blk = blockIdx.x;
    int tid = threadIdx.x;
    if (blk < 1024) {                 // ---- vtrans
        int s0 = (blk & 31) * 64;
        int bh = blk >> 5;
        int b = bh >> 4, h = bh & 15;
        int d = tid & 63;
#pragma unroll
        for (int i = tid >> 6; i < 64; i += 4)
            tile[i][d] = V[((size_t)(b * S_ + s0 + i)) * E_ + h * 64 + d];
        __syncthreads();
        int lane = tid & 63, w = tid >> 6;
        int src = ((lane & 3) * 16) + (lane >> 2);   // pi(lane)
#pragma unroll
        for (int dd = w; dd < 64; dd += 4)
            Vt[((size_t)(bh * 64 + dd)) * S_ + s0 + lane] = f2bf(tile[src][dd]);
        return;
    }
    // ---- prep_bias
    int L = blk - 1024;
    int qi = (int)((sqrtf(8.0f * (float)L + 1.0f) - 1.0f) * 0.5f);
    while ((qi + 1) * (qi + 2) / 2 <= L) qi++;
    while (qi * (qi + 1) / 2 > L) qi--;
    int ki = L - qi * (qi + 1) / 2;
    int w = tid >> 6, quad = (tid >> 4) & 3, l15 = tid & 15;
    const float LOG2E = 1.4426950408889634f;
    s16x8 h0 = (s16x8){0,0,0,0,0,0,0,0}, h1 = (s16x8){0,0,0,0,0,0,0,0};
#pragma unroll
    for (int r = 0; r < 4; r++)
#pragma unroll
        for (int kt = 0; kt < 4; kt++) {
            float v = bias[(size_t)(qi * 64 + w * 16 + quad * 4 + r) * S_
                           + ki * 64 + kt * 16 + l15] * LOG2E;
            ushort u = f2bf(v);
            int idx = r * 4 + kt;
            if (idx < 8) h0[idx] = (short)u; else h1[idx - 8] = (short)u;
        }
    ushort* dst = &biasT[((size_t)L * 256 + tid) * 16];
    *(s16x8*)dst = h0;
    *(s16x8*)(dst + 8) = h1;
}

// ---------------------------------------------------------------------------
// bf16 MFMA GEMM — BK=64 + XOR-swizzled LDS via pre-swizzled global source
// (unchanged from round 14; verified: dropped from 77us out of top-5).
// ---------------------------------------------------------------------------
__global__ __launch_bounds__(256) void gemm_mfma_bt(
    const ushort* __restrict__ A,    // [M][K] bf16
    const ushort* __restrict__ Bt,   // [N][K] bf16
    const float* __restrict__ bias,  // [N]
    int M, int N, int K,
    float* __restrict__ C0,
    ushort* __restrict__ Qbf, float* __restrict__ Kf32, ushort* __restrict__ Kbf,
    float* __restrict__ Vf32, int mode)
{
    __shared__ ushort As[128 * 64];
    __shared__ ushort Bs[128 * 64];
    int tid = threadIdx.x;
    int wid = tid >> 6, lane = tid & 63;
    int l15 = lane & 15, quad = lane >> 4;
    int wm = wid >> 1, wn = wid & 1;
    int row0 = blockIdx.y * 128, col0 = blockIdx.x * 128;

    int srow = tid >> 3;                         // 0..31 (row within round)
    int pk = (tid & 7) * 8;                      // physical chunk (LDS, linear)
    int sk = (((tid & 7) ^ (srow & 7)) * 8);     // logical chunk (global src)

    f32x4 acc[4][4];
#pragma unroll
    for (int mt = 0; mt < 4; mt++)
#pragma unroll
        for (int nt = 0; nt < 4; nt++) acc[mt][nt] = (f32x4){0.f, 0.f, 0.f, 0.f};

    for (int k0 = 0; k0 < K; k0 += 64) {
        __syncthreads();
#pragma unroll
        for (int c = 0; c < 4; c++) {
            int r = c * 32 + srow;
            __builtin_amdgcn_global_load_lds(
                (const __attribute__((address_space(1))) unsigned int*)
                    &A[(size_t)(row0 + r) * K + k0 + sk],
                (__attribute__((address_space(3))) unsigned int*)&As[r * 64 + pk],
                16, 0, 0);
            __builtin_amdgcn_global_load_lds(
                (const __attribute__((address_space(1))) unsigned int*)
                    &Bt[(size_t)(col0 + r) * K + k0 + sk],
                (__attribute__((address_space(3))) unsigned int*)&Bs[r * 64 + pk],
                16, 0, 0);
        }
        __syncthreads();

#pragma unroll
        for (int kk = 0; kk < 2; kk++) {
            int xc = (((kk * 4 + quad) ^ (l15 & 7)) * 8);
            s16x8 af[4], bf[4];
#pragma unroll
            for (int mt = 0; mt < 4; mt++)
                af[mt] = *(const s16x8*)&As[(wm * 64 + mt * 16 + l15) * 64 + xc];
#pragma unroll
            for (int nt = 0; nt < 4; nt++)
                bf[nt] = *(const s16x8*)&Bs[(wn * 64 + nt * 16 + l15) * 64 + xc];
#pragma unroll
            for (int mt = 0; mt < 4; mt++)
#pragma unroll
                for (int nt = 0; nt < 4; nt++)
                    acc[mt][nt] = __builtin_amdgcn_mfma_f32_16x16x32_bf16(
                        af[mt], bf[nt], acc[mt][nt], 0, 0, 0);
        }
    }

#pragma unroll
    for (int nt = 0; nt < 4; nt++) {
        int n = col0 + wn * 64 + nt * 16 + l15;
        float bv = bias[n];
        if (mode == 1) {
            int seg = n >> 10;
            int nn = n & (E_ - 1);
#pragma unroll
            for (int mt = 0; mt < 4; mt++)
#pragma unroll
                for (int r = 0; r < 4; r++) {
                    int row = row0 + wm * 64 + mt * 16 + quad * 4 + r;
                    float v = acc[mt][nt][r] + bv;
                    size_t idx = (size_t)row * E_ + nn;
                    if (seg == 0)      Qbf[idx] = f2bf(v);
                    else if (seg == 1) { Kf32[idx] = v; Kbf[idx] = f2bf(v); }
                    else               Vf32[idx] = v;
                }
        } else {
#pragma unroll
            for (int mt = 0; mt < 4; mt++)
#pragma unroll
                for (int r = 0; r < 4; r++) {
                    int row = row0 + wm * 64 + mt * 16 + quad * 4 + r;
                    C0[(size_t)row * N + n] = acc[mt][nt][r] + bv;
                }
        }
    }
}

// ---------------------------------------------------------------------------
// MFMA flash attention, fixed-reference softmax — round 15.
// R9 LDS-pipe budget: ~770cy/iter of 1660cy wall, x2 resident blocks = ~92%
// LDS occupancy, with the 2-barrier-per-tile chain (bar, stage, bar, read)
// exposing it serially.  Change: DOUBLE-BUFFERED Ks/Vs, ONE barrier per tile.
//  - compute at tile t reads buf[t&1] immediately at loop top;
//  - staging for tile t+1 (regs prefetched during t-1; global prefetch runs
//    two tiles ahead — R4's proven K-pipeline) writes buf[(t+1)&1] in
//    parallel with compute;
//  - the single end-of-iteration barrier covers RAW (next tile's reads) and
//    WAR (buffer reuse).  Prologue stages buf0 + loads tile1 + bias tile0.
// Everything else proven & unchanged: Ps b64 cvt_pk pack (key-permuted, pi in
// vtrans), biasT bf16 + exp2-direct, K/V XOR chunk swizzle, bh=blk&31 XCD
// mapping, 512 uniform paired blocks.  LDS 36.5KB (cap 4 blocks/CU; grid
// keeps 2).
// ---------------------------------------------------------------------------
__global__ __launch_bounds__(256) void attn_mfma_kernel(
    const ushort* __restrict__ Qbf,   // [B*S, E] bf16
    const ushort* __restrict__ Kbf,   // [B*S, E] bf16
    const ushort* __restrict__ Vt,    // [(b*H+h)*64+d][s] bf16, key-permuted
    const ushort* __restrict__ biasT, // causal-packed bf16 tiles
    ushort* __restrict__ Ctx)         // [B*S, E] bf16
{
    __shared__ ushort Ks[2][64][64];
    __shared__ ushort Vs[2][64][64];
    __shared__ ushort Ps[4][16][72];

    int blk = blockIdx.x;
    int bh = blk & 31;               // XCD = bh%8 -> K/V L2 locality
    int pr = blk >> 5;               // 0..15
    int b = bh >> 4, h = bh & 15;
    int tid = threadIdx.x;
    int wid = tid >> 6, lane = tid & 63;
    int l15 = lane & 15, quad = lane >> 4;

    int skey = tid >> 2;
    int scol = (tid & 3) * 16;       // ushort col of this thread's 16B pair
    int sc0 = ((((tid & 3) * 2) ^ (skey & 7)) * 8);
    int sc1 = sc0 ^ 8;
    const float scale_l2e = 0.18033688011112042f;   // 0.125 * log2(e)

    const size_t krow = (size_t)(b * S_ + skey) * E_ + h * 64 + scol; // + j0*E_
    const size_t vrow = (size_t)(bh * 64 + skey) * S_ + scol;        // + j0
    int rc0 = (quad ^ (l15 & 7)) * 8;

    for (int half = 0; half < 2; half++) {
        int qt = half ? pr : (31 - pr);
        int q0w = qt * 64 + wid * 16;

        // Q fragments (A-layout)
        const size_t qbase = ((size_t)(b * S_ + q0w + l15)) * E_ + h * 64 + quad * 8;
        s16x8 qa0 = *(const s16x8*)&Qbf[qbase];
        s16x8 qa1 = *(const s16x8*)&Qbf[qbase + 32];

        f32x4 o[4];
#pragma unroll
        for (int dt = 0; dt < 4; dt++) o[dt] = (f32x4){0.f, 0.f, 0.f, 0.f};
        float lsum[4];
#pragma unroll
        for (int r = 0; r < 4; r++) lsum[r] = 0.f;

        // ---- prologue: stage tile 0 into buf0; prefetch tile 1 into regs;
        //      load bias tile 0 into bn.
        {
            float4 k0a = ((const float4*)&Kbf[krow])[0];
            float4 k0b = ((const float4*)&Kbf[krow])[1];
            float4 v0a = ((const float4*)&Vt[vrow])[0];
            float4 v0b = ((const float4*)&Vt[vrow])[1];
            *(float4*)&Ks[0][skey][sc0] = k0a;
            *(float4*)&Ks[0][skey][sc1] = k0b;
            *(float4*)&Vs[0][skey][sc0] = v0a;
            *(float4*)&Vs[0][skey][sc1] = v0b;
        }
        float4 kr0, kr1, vr0, vr1;
        if (qt >= 1) {
            kr0 = ((const float4*)&Kbf[krow + (size_t)64 * E_])[0];
            kr1 = ((const float4*)&Kbf[krow + (size_t)64 * E_])[1];
            vr0 = ((const float4*)&Vt[vrow + 64])[0];
            vr1 = ((const float4*)&Vt[vrow + 64])[1];
        }
        const ushort* bt = &biasT[((size_t)(qt * (qt + 1) / 2) * 256 + tid) * 16];
        s16x8 bn0 = *(const s16x8*)bt;
        s16x8 bn1 = *(const s16x8*)(bt + 8);
        __syncthreads();              // buf0 visible to all waves

        for (int t = 0; t <= qt; t++) {
            int j0 = t * 64;
            int cur = t & 1, nxt = cur ^ 1;

            // ---- stage tile t+1 from regs (overlaps with this tile's compute)
            if (t < qt) {
                *(float4*)&Ks[nxt][skey][sc0] = kr0;
                *(float4*)&Ks[nxt][skey][sc1] = kr1;
                *(float4*)&Vs[nxt][skey][sc0] = vr0;
                *(float4*)&Vs[nxt][skey][sc1] = vr1;
            }
            // ---- prefetch tile t+2 into regs (one full tile to cover latency)
            if (t + 2 <= qt) {
                size_t koff = krow + (size_t)((t + 2) * 64) * E_;
                kr0 = ((const float4*)&Kbf[koff])[0];
                kr1 = ((const float4*)&Kbf[koff])[1];
                vr0 = ((const float4*)&Vt[vrow + (t + 2) * 64])[0];
                vr1 = ((const float4*)&Vt[vrow + (t + 2) * 64])[1];
            }
            // ---- bias: copy current, prefetch next
            s16x8 b0 = bn0, b1 = bn1;
            if (t < qt) {
                const ushort* btn = bt + (size_t)(t + 1) * 4096;
                bn0 = *(const s16x8*)btn;
                bn1 = *(const s16x8*)(btn + 8);
            }

            // ---- S = Q K^T from Ks[cur]
            f32x4 s[4];
#pragma unroll
            for (int kt = 0; kt < 4; kt++) {
                s16x8 kb0 = *(const s16x8*)&Ks[cur][kt * 16 + l15][rc0];
                s16x8 kb1 = *(const s16x8*)&Ks[cur][kt * 16 + l15][rc0 ^ 32];
                f32x4 acc = (f32x4){0.f, 0.f, 0.f, 0.f};
                acc = __builtin_amdgcn_mfma_f32_16x16x32_bf16(qa0, kb0, acc, 0, 0, 0);
                acc = __builtin_amdgcn_mfma_f32_16x16x32_bf16(qa1, kb1, acc, 0, 0, 0);
                s[kt] = acc;
            }

            // ---- p = exp2(s*scale + biasT); causal mask; packed b64 Ps write
            bool diag = (t == qt);
#pragma unroll
            for (int r = 0; r < 4; r++) {
                int row = q0w + quad * 4 + r;
                float pv[4];
#pragma unroll
                for (int kt = 0; kt < 4; kt++) {
                    int j = j0 + kt * 16 + l15;
                    int idx = r * 4 + kt;
                    ushort ub = (ushort)((idx < 8) ? b0[idx] : b1[idx - 8]);
                    union { unsigned u; float f; } bc; bc.u = ((unsigned)ub) << 16;
                    float v = fmaf(s[kt][r], scale_l2e, bc.f);
                    float p = (diag && j > row) ? 0.f : fast_exp2(v);
                    lsum[r] += p;
                    pv[kt] = p;
                }
                unsigned w0, w1;
                asm("v_cvt_pk_bf16_f32 %0, %1, %2" : "=v"(w0) : "v"(pv[0]), "v"(pv[1]));
                asm("v_cvt_pk_bf16_f32 %0, %1, %2" : "=v"(w1) : "v"(pv[2]), "v"(pv[3]));
                uint2 wv; wv.x = w0; wv.y = w1;
                *(uint2*)&Ps[wid][quad * 4 + r][l15 * 4] = wv;
            }

            // ---- O += P V  (Ps wave-private: no barrier; permuted key dim)
            s16x8 pa0 = *(const s16x8*)&Ps[wid][l15][quad * 8];
            s16x8 pa1 = *(const s16x8*)&Ps[wid][l15][32 + quad * 8];
#pragma unroll
            for (int dt = 0; dt < 4; dt++) {
                s16x8 vb0 = *(const s16x8*)&Vs[cur][dt * 16 + l15][rc0];
                s16x8 vb1 = *(const s16x8*)&Vs[cur][dt * 16 + l15][rc0 ^ 32];
                o[dt] = __builtin_amdgcn_mfma_f32_16x16x32_bf16(pa0, vb0, o[dt], 0, 0, 0);
                o[dt] = __builtin_amdgcn_mfma_f32_16x16x32_bf16(pa1, vb1, o[dt], 0, 0, 0);
            }

            __syncthreads();   // staging of nxt visible; cur released
        }

        // ---- single final row-sum reduction
        float inv_l[4];
#pragma unroll
        for (int r = 0; r < 4; r++) {
            float l = lsum[r];
            l += __shfl_xor(l, 1);
            l += __shfl_xor(l, 2);
            l += __shfl_xor(l, 4);
            l += __shfl_xor(l, 8);
            inv_l[r] = 1.f / l;
        }

#pragma unroll
        for (int dt = 0; dt < 4; dt++) {
#pragma unroll
            for (int r = 0; r < 4; r++) {
                int row = q0w + quad * 4 + r;
                Ctx[((size_t)(b * S_ + row)) * E_ + h * 64 + dt * 16 + l15] =
                    f2bf(o[dt][r] * inv_l[r]);
            }
        }
    }
}

// ---------------------------------------------------------------------------
extern "C" void kernel_launch(void* const* d_in, const int* in_sizes, int n_in,
                              void* d_out, int out_size, void* d_ws, size_t ws_size,
                              hipStream_t stream) {
    const float* X     = (const float*)d_in[0];
    const float* abias = (const float*)d_in[1];
    const float* Wqkv  = (const float*)d_in[2];
    const float* bqkv  = (const float*)d_in[3];
    const float* Wproj = (const float*)d_in[4];
    const float* bproj = (const float*)d_in[5];

    const size_t plane = (size_t)B_ * S_ * E_;   // 4,194,304
    float* out  = (float*)d_out;
    float* kout = out + plane;                   // cache_key (fp32 output)
    float* vout = kout + plane;                  // cache_value (fp32 output)

    // workspace: 4 bf16 planes + weights = 42 MB (proven footprint).
    // ctxbf ALIASES xbf (X's bf16 copy is dead after the QKV GEMM).
    // biasT ALIASES wqkvt (Wqkv^T dead after the QKV GEMM; 4.3MB <= 6MB).
    ushort* xbf    = (ushort*)d_ws;
    ushort* qbf    = xbf + plane;
    ushort* kbf    = qbf + plane;
    ushort* vt     = kbf + plane;
    ushort* ctxbf  = xbf;                        // alias (see above)
    ushort* wqkvt  = vt + plane;                 // [3E][E]
    ushort* wprojt = wqkvt + (size_t)3 * E_ * E_;// [E][E]
    ushort* biasT  = wqkvt;                      // alias (see above)

    const int M = B_ * S_;

    // fused: cvtx (4096 blocks) + Wqkv^T (768) + Wproj^T (256)
    prep_fused_kernel<<<dim3(5120), 256, 0, stream>>>(
        X, xbf, Wqkv, wqkvt, Wproj, wprojt);

    gemm_mfma_bt<<<dim3(3 * E_ / 128, M / 128), 256, 0, stream>>>(
        xbf, wqkvt, bqkv, M, 3 * E_, E_,
        nullptr, qbf, kout, kbf, vout, 1);

    // fused: vtrans (1024 blocks) + bias pre-pack (528 blocks)
    post_qkv_kernel<<<dim3(1024 + 528), 256, 0, stream>>>(
        vout, vt, abias, biasT);

    // flash attention: 512 paired blocks; XCD = bh%8 for K/V L2 locality
    attn_mfma_kernel<<<dim3(B_ * H_ * 16), 256, 0, stream>>>(
        qbf, kbf, vt, biasT, ctxbf);

    gemm_mfma_bt<<<dim3(E_ / 128, M / 128), 256, 0, stream>>>(
        ctxbf, wprojt, bproj, M, E_, E_,
        out, nullptr, nullptr, nullptr, nullptr, 0);
}